// Round 16
// baseline (1184.830 us; speedup 1.0000x reference)
//
#include <hip/hip_runtime.h>
#include <hip/hip_bf16.h>
#include <stdint.h>
#include <stddef.h>

#define GLOBAL_AS __attribute__((address_space(1)))
#define LDS_AS __attribute__((address_space(3)))

typedef __attribute__((ext_vector_type(4))) float f32x4;
typedef __attribute__((ext_vector_type(8))) short bf16x8;
typedef __attribute__((ext_vector_type(4))) int   i32x4;

template<int N> struct ICn { static constexpr int value = N; };

__device__ __forceinline__ unsigned short f2bf(float f) {
  unsigned u = __float_as_uint(f);
  u += 0x7FFFu + ((u >> 16) & 1u);   // round-to-nearest-even
  return (unsigned short)(u >> 16);
}

__device__ __forceinline__ void load_lds16(const void* g, void* l) {
  __builtin_amdgcn_global_load_lds((const GLOBAL_AS void*)g, (LDS_AS void*)l, 16, 0, 0);
}

// ds_read_b128 with compile-time offset immediate; address VALU-free.
template<int IMM, typename T>
__device__ __forceinline__ void ds_read128t(T &d, unsigned addr) {
  asm volatile("ds_read_b128 %0, %1 offset:%c2"
               : "=&v"(d) : "v"(addr), "i"(IMM));
}

#define SBAR0 __builtin_amdgcn_sched_barrier(0)

#define WAITV(N) do { SBAR0; \
  asm volatile("s_waitcnt vmcnt(" #N ")" ::: "memory"); SBAR0; } while (0)

#define WAITVL(N) do { SBAR0; \
  asm volatile("s_waitcnt vmcnt(" #N ") lgkmcnt(0)" ::: "memory"); SBAR0; } while (0)

#define LGKMW(N) do { SBAR0; \
  asm volatile("s_waitcnt lgkmcnt(" #N ")" ::: "memory"); SBAR0; } while (0)

// ---------------------------------------------------------------------------
// Detect int8 vs int32 storage of the ternary weights (see round-0 notes).
// ---------------------------------------------------------------------------
__global__ __launch_bounds__(256) void detect_dtype_k(const int* __restrict__ w,
                                                      int* __restrict__ flag) {
  __shared__ int bad;
  if (threadIdx.x == 0) bad = 0;
  __syncthreads();
  int b = 0;
  for (int i = threadIdx.x; i < 4096; i += 256) {
    int v = w[i];
    if (v < -1 || v > 1) b = 1;
  }
  if (b) bad = 1;
  __syncthreads();
  if (threadIdx.x == 0) *flag = bad ? 0 : 1;
}

// ---------------------------------------------------------------------------
// x0[t][h] = bf16(emb[ids[t]][h])
// ---------------------------------------------------------------------------
__global__ __launch_bounds__(256) void gather_emb_k(const int* __restrict__ ids,
                                                    const float* __restrict__ emb,
                                                    unsigned short* __restrict__ x) {
  const int t = blockIdx.x;
  const int row = ids[t];
  const float4* src = (const float4*)(emb + (size_t)row * 2048);
  const int e = threadIdx.x;
  float4 a = src[e * 2], b = src[e * 2 + 1];
  uint4 o;
  o.x = f2bf(a.x) | ((unsigned)f2bf(a.y) << 16);
  o.y = f2bf(a.z) | ((unsigned)f2bf(a.w) << 16);
  o.z = f2bf(b.x) | ((unsigned)f2bf(b.y) << 16);
  o.w = f2bf(b.z) | ((unsigned)f2bf(b.w) << 16);
  *(uint4*)(x + (size_t)t * 2048 + e * 8) = o;
}

// ---------------------------------------------------------------------------
// ternary int8-or-int32 -> bf16 (hidden-layer weights)
// ---------------------------------------------------------------------------
__global__ __launch_bounds__(256) void convert_w_k(const void* __restrict__ src,
                                                   unsigned short* __restrict__ dst,
                                                   const int* __restrict__ flag) {
  const long long idx = ((long long)blockIdx.x * 256 + threadIdx.x) * 8;
  int v[8];
  if (*flag) {
    const int* s = (const int*)src + idx;
    const int4 a = *(const int4*)s;
    const int4 b = *(const int4*)(s + 4);
    v[0] = a.x; v[1] = a.y; v[2] = a.z; v[3] = a.w;
    v[4] = b.x; v[5] = b.y; v[6] = b.z; v[7] = b.w;
  } else {
    const uint2 u = *(const uint2*)((const char*)src + idx);
    v[0] = (char)(u.x); v[1] = (char)(u.x >> 8); v[2] = (char)(u.x >> 16); v[3] = (char)(u.x >> 24);
    v[4] = (char)(u.y); v[5] = (char)(u.y >> 8); v[6] = (char)(u.y >> 16); v[7] = (char)(u.y >> 24);
  }
  unsigned short o[8];
  #pragma unroll
  for (int k = 0; k < 8; ++k)
    o[k] = (v[k] == 0) ? 0 : ((v[k] > 0) ? 0x3F80 : 0xBF80);
  uint4 w;
  w.x = o[0] | ((unsigned)o[1] << 16);
  w.y = o[2] | ((unsigned)o[3] << 16);
  w.z = o[4] | ((unsigned)o[5] << 16);
  w.w = o[6] | ((unsigned)o[7] << 16);
  *(uint4*)(dst + idx) = w;
}

// ---------------------------------------------------------------------------
// ternary int32 -> int8 pack (output weights). Early-exit if already int8.
// ---------------------------------------------------------------------------
__global__ __launch_bounds__(256) void pack_w8_k(const void* __restrict__ src,
                                                 signed char* __restrict__ dst,
                                                 const int* __restrict__ flag) {
  if (!*flag) return;   // already int8: consumers read the input directly
  const long long idx = ((long long)blockIdx.x * 256 + threadIdx.x) * 8;
  const int* s = (const int*)src + idx;
  const int4 a = *(const int4*)s;
  const int4 b = *(const int4*)(s + 4);
  uint2 o;
  o.x = ((unsigned)(unsigned char)(signed char)a.x)       |
        ((unsigned)(unsigned char)(signed char)a.y << 8)  |
        ((unsigned)(unsigned char)(signed char)a.z << 16) |
        ((unsigned)(unsigned char)(signed char)a.w << 24);
  o.y = ((unsigned)(unsigned char)(signed char)b.x)       |
        ((unsigned)(unsigned char)(signed char)b.y << 8)  |
        ((unsigned)(unsigned char)(signed char)b.z << 16) |
        ((unsigned)(unsigned char)(signed char)b.w << 24);
  *(uint2*)(dst + idx) = o;
}

// ---------------------------------------------------------------------------
// colsum_c = sum_k w8[c][k]  (ternary row sums, fp32 out).  1 wave per col.
// ---------------------------------------------------------------------------
__global__ __launch_bounds__(256) void colsum_k(const signed char* __restrict__ wp,
                                                const signed char* __restrict__ wr,
                                                const int* __restrict__ flag,
                                                float* __restrict__ cs) {
  const signed char* w = (*flag) ? wp : wr;
  const int lane = threadIdx.x & 63;
  const int c = blockIdx.x * 4 + (threadIdx.x >> 6);
  const int4* p = (const int4*)(w + (size_t)c * 2048 + lane * 32);
  const int4 a = p[0], b = p[1];
  int wds[8] = {a.x, a.y, a.z, a.w, b.x, b.y, b.z, b.w};
  int s = 0;
  #pragma unroll
  for (int k = 0; k < 8; ++k)
    #pragma unroll
    for (int bb = 0; bb < 4; ++bb)
      s += (signed char)(wds[k] >> (8 * bb));
  #pragma unroll
  for (int o = 32; o; o >>= 1) s += __shfl_xor(s, o);
  if (lane == 0) cs[c] = (float)s;
}

// ---------------------------------------------------------------------------
// Per-row offset quantization of final x: s=rowmax/255, m=127.5s,
// q = round(x/s - 127.5) in [-128,127].  One block per row.
// ---------------------------------------------------------------------------
__global__ __launch_bounds__(256) void rowquant_k(const unsigned short* __restrict__ x,
                                                  signed char* __restrict__ xq,
                                                  float* __restrict__ srow) {
  __shared__ float wmax[4];
  const int r = blockIdx.x;
  const int e = threadIdx.x;
  const uint4 u = *(const uint4*)(x + (size_t)r * 2048 + e * 8);
  unsigned wds[4] = {u.x, u.y, u.z, u.w};
  float v[8];
  #pragma unroll
  for (int k = 0; k < 4; ++k) {
    v[2 * k]     = __uint_as_float(wds[k] << 16);
    v[2 * k + 1] = __uint_as_float(wds[k] & 0xFFFF0000u);
  }
  float m = 0.0f;                       // x >= 0 post-ReLU
  #pragma unroll
  for (int k = 0; k < 8; ++k) m = fmaxf(m, v[k]);
  #pragma unroll
  for (int o = 32; o; o >>= 1) m = fmaxf(m, __shfl_xor(m, o));
  if ((threadIdx.x & 63) == 0) wmax[threadIdx.x >> 6] = m;
  __syncthreads();
  const float mx = fmaxf(fmaxf(wmax[0], wmax[1]), fmaxf(wmax[2], wmax[3]));
  const float inv = mx > 0.0f ? 255.0f / mx : 0.0f;
  unsigned b[8];
  #pragma unroll
  for (int k = 0; k < 8; ++k) {
    int q = __float2int_rn(v[k] * inv - 127.5f);
    q = q < -128 ? -128 : (q > 127 ? 127 : q);
    b[k] = (unsigned)(unsigned char)(signed char)q;
  }
  uint2 o;
  o.x = b[0] | (b[1] << 8) | (b[2] << 16) | (b[3] << 24);
  o.y = b[4] | (b[5] << 8) | (b[6] << 16) | (b[7] << 24);
  *(uint2*)(xq + (size_t)r * 2048 + e * 8) = o;
  if (threadIdx.x == 0) srow[r] = mx * (1.0f / 255.0f);
}

// ---------------------------------------------------------------------------
// Hidden-layer GEMM v2 (r12, passing).
// ---------------------------------------------------------------------------
__global__ __launch_bounds__(256, 2) void gemm_bt2_k(
    const unsigned short* __restrict__ A,
    const unsigned short* __restrict__ Bw,
    const float* __restrict__ scale,
    const float* __restrict__ bias,
    unsigned short* __restrict__ Cout,
    int M, int N, int K)
{
  __shared__ unsigned short As[2 * 8192];
  __shared__ unsigned short Bs[2 * 8192];

  const int tid  = threadIdx.x;
  const int lane = tid & 63;
  const int wid  = tid >> 6;
  const int wm   = wid >> 1;
  const int wn   = wid & 1;
  const int l15  = lane & 15;
  const int l4   = lane >> 4;

  const int mBase = blockIdx.y * 128;
  const int nBase = blockIdx.x * 128;

  const int gsw = ((lane & 7) ^ (lane >> 3)) * 8;

  const unsigned asB = (unsigned)(size_t)(const LDS_AS unsigned short*)As;
  const unsigned bsB = (unsigned)(size_t)(const LDS_AS unsigned short*)Bs;
  const unsigned x7  = (unsigned)(l15 & 7);
  const unsigned vA0 = asB + (wm << 13) + l15 * 128 + ((((unsigned)l4    ) ^ x7) << 4);
  const unsigned vA1 = asB + (wm << 13) + l15 * 128 + ((((unsigned)l4 + 4) ^ x7) << 4);
  const unsigned vB0 = bsB + (wn << 13) + l15 * 128 + ((((unsigned)l4    ) ^ x7) << 4);
  const unsigned vB1 = bsB + (wn << 13) + l15 * 128 + ((((unsigned)l4 + 4) ^ x7) << 4);

  const unsigned short* pA[4];
  const unsigned short* pB[4];
  #pragma unroll
  for (int j = 0; j < 4; ++j) {
    const int row = (wid * 4 + j) * 8 + (lane >> 3);
    pA[j] = A  + (size_t)(mBase + row) * K + gsw;
    pB[j] = Bw + (size_t)(nBase + row) * K + gsw;
  }

  f32x4 acc[4][4];
  #pragma unroll
  for (int i = 0; i < 4; ++i)
    #pragma unroll
    for (int j = 0; j < 4; ++j)
      acc[i][j] = (f32x4){0.f, 0.f, 0.f, 0.f};

  const int nt = K >> 6;

  #pragma unroll
  for (int j = 0; j < 4; ++j)
    load_lds16(pA[j], As + (wid * 4 + j) * 512);
  #pragma unroll
  for (int j = 0; j < 4; ++j)
    load_lds16(pB[j], Bs + (wid * 4 + j) * 512);
  #pragma unroll
  for (int j = 0; j < 4; ++j) { pA[j] += 64; pB[j] += 64; }
  WAITV(0);
  __builtin_amdgcn_s_barrier();

  bf16x8 afA[4], afB[4], bfrA[4], bfrB[4];

  for (int t = 0; t < nt; ++t) {
    const unsigned po = (unsigned)(t & 1) * 16384u;
    const unsigned aA0 = vA0 + po, aA1 = vA1 + po;
    const unsigned aB0 = vB0 + po, aB1 = vB1 + po;
    unsigned short* dA = As + (size_t)((t + 1) & 1) * 8192;
    unsigned short* dB = Bs + (size_t)((t + 1) & 1) * 8192;
    const bool st = (t + 1 < nt);

    ds_read128t<0   >(afA[0], aA0); ds_read128t<2048>(afA[1], aA0);
    ds_read128t<4096>(afA[2], aA0); ds_read128t<6144>(afA[3], aA0);
    ds_read128t<0   >(bfrA[0], aB0); ds_read128t<2048>(bfrA[1], aB0);
    ds_read128t<4096>(bfrA[2], aB0); ds_read128t<6144>(bfrA[3], aB0);
    ds_read128t<0   >(afB[0], aA1); ds_read128t<2048>(afB[1], aA1);
    ds_read128t<4096>(afB[2], aA1); ds_read128t<6144>(afB[3], aA1);
    ds_read128t<0   >(bfrB[0], aB1); ds_read128t<2048>(bfrB[1], aB1);
    ds_read128t<4096>(bfrB[2], aB1); ds_read128t<6144>(bfrB[3], aB1);
    #pragma unroll
    for (int j = 0; j < 4; ++j)
      load_lds16(st ? pA[j] : A, dA + (wid * 4 + j) * 512);
    #pragma unroll
    for (int j = 0; j < 4; ++j)
      load_lds16(st ? pB[j] : Bw, dB + (wid * 4 + j) * 512);
    #pragma unroll
    for (int j = 0; j < 4; ++j) { pA[j] += 64; pB[j] += 64; }

    LGKMW(8);
    __builtin_amdgcn_s_setprio(1);
    #pragma unroll
    for (int i = 0; i < 4; ++i)
      #pragma unroll
      for (int j = 0; j < 4; ++j)
        acc[i][j] = __builtin_amdgcn_mfma_f32_16x16x32_bf16(afA[i], bfrA[j], acc[i][j], 0, 0, 0);
    __builtin_amdgcn_s_setprio(0);
    SBAR0;
    LGKMW(0);
    __builtin_amdgcn_s_setprio(1);
    #pragma unroll
    for (int i = 0; i < 4; ++i)
      #pragma unroll
      for (int j = 0; j < 4; ++j)
        acc[i][j] = __builtin_amdgcn_mfma_f32_16x16x32_bf16(afB[i], bfrB[j], acc[i][j], 0, 0, 0);
    __builtin_amdgcn_s_setprio(0);
    SBAR0;
    WAITV(0);
    __builtin_amdgcn_s_barrier();
  }

  const int lr = l4;
  const int lc = l15;
  #pragma unroll
  for (int j = 0; j < 4; ++j) {
    const int col = nBase + wn * 64 + j * 16 + lc;
    const float sc = scale[col];
    const float bs = bias[col];
    #pragma unroll
    for (int i = 0; i < 4; ++i) {
      const int r0 = mBase + wm * 64 + i * 16 + lr * 4;
      #pragma unroll
      for (int r = 0; r < 4; ++r) {
        float vv = fmaxf(acc[i][j][r] * sc + bs, 0.0f);
        Cout[(size_t)(r0 + r) * N + col] = f2bf(vv);
      }
    }
  }
}

// ---------------------------------------------------------------------------
// Final GEMM v10: 16-wave occupancy variant (4 waves/SIMD).
// 256x256 tile, BK=128 i8, 16 K-tiles, 16 waves (4M x 4N, 64x64/wave),
// dbuf LDS (128 KiB, 1 block/CU).  acc = 4x4 frags = 64 AGPR; VGPR ~70
// -> <=128 regs/wave -> 4 waves/SIMD (2x round-15 occupancy).
// Per tile: {issue A8 + B cols 0,1 || stage FULL tile t+1 into opposite
// buffer -> 4 col-phases (8 MFMA each) with counted lgkmcnt(2) B-col
// read-ahead -> vmcnt(0) -> ONE barrier}.  Hazards: stage writes only the
// dead buffer; each wave's reads retire (LGKMW(0)) before its barrier ->
// write-after-read safe; WAITV(0)+barrier makes stage visible to all.
// Epilogue: logit = dotq*(s_r*scale_c) + 127.5*s_r*colsum_c*scale_c + bias_c
// ---------------------------------------------------------------------------

#define RD_AF8() do { \
  ds_read128t<PAR*32768 +    0>(af[0][0], vA0); ds_read128t<PAR*32768 +    0>(af[0][1], vA1); \
  ds_read128t<PAR*32768 + 2048>(af[1][0], vA0); ds_read128t<PAR*32768 + 2048>(af[1][1], vA1); \
  ds_read128t<PAR*32768 + 4096>(af[2][0], vA0); ds_read128t<PAR*32768 + 4096>(af[2][1], vA1); \
  ds_read128t<PAR*32768 + 6144>(af[3][0], vA0); ds_read128t<PAR*32768 + 6144>(af[3][1], vA1); \
} while (0)

#define RD_BCOL(DST, J) do { \
  ds_read128t<PAR*32768 + (J)*2048>(DST[0], vB0); \
  ds_read128t<PAR*32768 + (J)*2048>(DST[1], vB1); \
} while (0)

#define MFMA_COL(J, B) do { \
  __builtin_amdgcn_s_setprio(1); \
  { _Pragma("unroll") for (int i_ = 0; i_ < 4; ++i_) { \
      acc[i_][J] = __builtin_amdgcn_mfma_i32_16x16x64_i8(af[i_][0], B[0], acc[i_][J], 0, 0, 0); \
      acc[i_][J] = __builtin_amdgcn_mfma_i32_16x16x64_i8(af[i_][1], B[1], acc[i_][J], 0, 0, 0); \
  } } \
  __builtin_amdgcn_s_setprio(0); \
  SBAR0; \
} while (0)

#define STAGE16(PARD) do { \
  load_lds16(st ? pA           : Aq, Asf + (PARD) * 32768 + wid * 2048); \
  load_lds16(st ? (pA + 16384) : Aq, Asf + (PARD) * 32768 + wid * 2048 + 1024); \
  load_lds16(st ? pB           : Bq, Bsf + (PARD) * 32768 + wid * 2048); \
  load_lds16(st ? (pB + 16384) : Bq, Bsf + (PARD) * 32768 + wid * 2048 + 1024); \
  pA += 128; pB += 128; \
} while (0)

__global__ __launch_bounds__(1024, 4) void gemm256i8_k(
    const signed char* __restrict__ Aq,
    const signed char* __restrict__ Bpk,
    const signed char* __restrict__ Braw,
    const int* __restrict__ flag,
    const float* __restrict__ scale,
    const float* __restrict__ bias,
    const float* __restrict__ srow,
    const float* __restrict__ colsum,
    float* __restrict__ C,
    int M, int N, int K)   // K in elements (=bytes)
{
  __shared__ signed char Asf[2 * 32768];
  __shared__ signed char Bsf[2 * 32768];

  const signed char* Bq = (*flag) ? Bpk : Braw;

  const int tid  = threadIdx.x;
  const int lane = tid & 63;
  const int wid  = tid >> 6;   // 0..15
  const int wm   = wid >> 2;   // 0..3  (64-row quarter)
  const int wn   = wid & 3;    // 0..3  (64-col quarter)
  const int l15  = lane & 15;
  const int l4   = lane >> 4;

  // bijective XCD swizzle (2000 = 8*250), then m-fastest for B reuse
  const int q    = gridDim.x >> 3;
  const int wgid = (blockIdx.x & 7) * q + (blockIdx.x >> 3);
  const int mBase = (wgid & 15) << 8;
  const int nBase = (wgid >> 4) << 8;

  const int gsw = ((lane & 7) ^ (lane >> 3)) * 16;   // bytes

  const unsigned asB = (unsigned)(size_t)(const LDS_AS signed char*)Asf;
  const unsigned bsB = (unsigned)(size_t)(const LDS_AS signed char*)Bsf;
  const unsigned x7  = (unsigned)(l15 & 7);
  // A: wave block = rows wm*64..wm*64+63 (wm<<13 bytes); frag i at +i*2048
  const unsigned vA0 = asB + (wm << 13) + l15 * 128 + ((((unsigned)l4    ) ^ x7) << 4);
  const unsigned vA1 = asB + (wm << 13) + l15 * 128 + ((((unsigned)l4 + 4) ^ x7) << 4);
  const unsigned vB0 = bsB + (wn << 13) + l15 * 128 + ((((unsigned)l4    ) ^ x7) << 4);
  const unsigned vB1 = bsB + (wn << 13) + l15 * 128 + ((((unsigned)l4 + 4) ^ x7) << 4);

  // stage sources: wave wid covers rows wid*16..wid*16+15 via 2 instr of
  // 8 rows; instr j: row wid*16 + j*8 + (lane>>3) -> src offset j*16384 B.
  const signed char* pA = Aq + (size_t)(mBase + wid * 16 + (lane >> 3)) * K + gsw;
  const signed char* pB = Bq + (size_t)(nBase + wid * 16 + (lane >> 3)) * K + gsw;

  i32x4 acc[4][4];
  #pragma unroll
  for (int i = 0; i < 4; ++i)
    #pragma unroll
    for (int j = 0; j < 4; ++j)
      acc[i][j] = (i32x4){0, 0, 0, 0};

  const int nt = K >> 7;   // 16 K-tiles (even)

  i32x4 af[4][2], bP[2], bQ[2];

  // ---- prologue: stage tile 0 -> buf 0 (4 instr/wave), drain, barrier ----
  {
    const bool st = true; (void)st;
    load_lds16(pA,         Asf + wid * 2048);
    load_lds16(pA + 16384, Asf + wid * 2048 + 1024);
    load_lds16(pB,         Bsf + wid * 2048);
    load_lds16(pB + 16384, Bsf + wid * 2048 + 1024);
    pA += 128; pB += 128;
  }
  WAITV(0);
  __builtin_amdgcn_s_barrier();

  auto tile_body = [&](int t, auto par_c) {
    constexpr int PAR = decltype(par_c)::value;
    const bool st = (t + 1 < nt);
    // ---- p0: issue A8 + B cols 0,1 (12 lgkm); stage t+1 -> dead buffer ----
    RD_AF8();
    RD_BCOL(bP, 0);
    RD_BCOL(bQ, 1);
    SBAR0;
    STAGE16(PAR ^ 1);
    LGKMW(2);                 // af + bP retired; bQ (2) in flight
    MFMA_COL(0, bP);
    // ---- p1 ----
    RD_BCOL(bP, 2);
    LGKMW(2);                 // bQ(col1) retired; col2 in flight
    MFMA_COL(1, bQ);
    // ---- p2 ----
    RD_BCOL(bQ, 3);
    LGKMW(2);                 // bP(col2) retired; col3 in flight
    MFMA_COL(2, bP);
    // ---- p3 ----
    LGKMW(0);                 // bQ(col3) retired
    MFMA_COL(3, bQ);
    WAITV(0);                 // stage(t+1) landed
    __builtin_amdgcn_s_barrier();
  };

  for (int t = 0; t < nt; t += 2) {
    tile_body(t,     ICn<0>{});
    tile_body(t + 1, ICn<1>{});
  }

  // full drain before VGPR reuse (r10 lesson; should be a no-op here)
  WAITVL(0);

  // epilogue: C/D layout col = lane&15, row = (lane>>4)*4 + reg (dtype-indep)
  #pragma unroll
  for (int j = 0; j < 4; ++j) {
    const int col = nBase + wn * 64 + j * 16 + l15;
    const float sc  = scale[col];
    const float csc = colsum[col] * sc;
    const float bs  = bias[col];
    #pragma unroll
    for (int i = 0; i < 4; ++i) {
      const int r0 = mBase + wm * 64 + i * 16 + l4 * 4;
      const f32x4 sv = *(const f32x4*)(srow + r0);
      #pragma unroll
      for (int r = 0; r < 4; ++r) {
        const float fa = (float)acc[i][j][r];
        C[(size_t)(r0 + r) * N + col] =
            fmaf(fa, sv[r] * sc, fmaf(127.5f * sv[r], csc, bs));
      }
    }
  }
}

// ---------------------------------------------------------------------------
extern "C" void kernel_launch(void* const* d_in, const int* in_sizes, int n_in,
                              void* d_out, int out_size, void* d_ws, size_t ws_size,
                              hipStream_t stream) {
  const int V = 32000, H = 2048, L = 4, M = 4096;
  const int*   ids         = (const int*)d_in[0];
  const float* emb         = (const float*)d_in[1];
  const void*  layer_wq    = d_in[2];
  const float* layer_scale = (const float*)d_in[3];
  const float* layer_bias  = (const float*)d_in[4];
  const void*  out_wq      = d_in[5];
  const float* out_scale   = (const float*)d_in[6];
  const float* out_bias    = (const float*)d_in[7];
  float* out = (float*)d_out;

  char* ws = (char*)d_ws;
  const size_t xBytes = (size_t)M * H * 2;
  unsigned short* xA  = (unsigned short*)(ws);
  unsigned short* xB  = (unsigned short*)(ws + xBytes);
  unsigned short* lw  = (unsigned short*)(ws + 2 * xBytes);
  size_t off = 2 * xBytes + (size_t)L * H * H * 2;
  signed char* ow8    = (signed char*)(ws + off);   off += (size_t)V * H;
  signed char* xq     = (signed char*)(ws + off);   off += (size_t)M * H;
  float* srow         = (float*)(ws + off);         off += (size_t)M * 4;
  float* cs           = (float*)(ws + off);         off += (size_t)V * 4;
  int* flag           = (int*)(ws + off);

  detect_dtype_k<<<1, 256, 0, stream>>>((const int*)layer_wq, flag);
  gather_emb_k<<<M, 256, 0, stream>>>(ids, emb, xA);
  convert_w_k<<<(L * H * H) / 2048, 256, 0, stream>>>(layer_wq, lw, flag);
  pack_w8_k<<<(V * H) / 2048, 256, 0, stream>>>(out_wq, ow8, flag);
  colsum_k<<<V / 4, 256, 0, stream>>>(ow8, (const signed char*)out_wq, flag, cs);

  dim3 blk(256);
  dim3 gh(H / 128, M / 128);
  unsigned short* xin = xA;
  unsigned short* xout = xB;
  for (int i = 0; i < L; ++i) {
    gemm_bt2_k<<<gh, blk, 0, stream>>>(xin, lw + (size_t)i * H * H,
                                       layer_scale + i * H, layer_bias + i * H,
                                       xout, M, H, H);
    unsigned short* t = xin; xin = xout; xout = t;
  }

  rowquant_k<<<M, 256, 0, stream>>>(xin, xq, srow);

  // final: (M/256)*(V/256) = 16*125 = 2000 blocks x 1024 threads
  gemm256i8_k<<<dim3(2000), dim3(1024), 0, stream>>>(
      xq, ow8, (const signed char*)out_wq, flag,
      out_scale, out_bias, srow, cs, out, M, V, H);
}

// Round 17
// 626.819 us; speedup vs baseline: 1.8902x; 1.8902x over previous
//
#include <hip/hip_runtime.h>
#include <hip/hip_bf16.h>
#include <stdint.h>
#include <stddef.h>

#define GLOBAL_AS __attribute__((address_space(1)))
#define LDS_AS __attribute__((address_space(3)))

typedef __attribute__((ext_vector_type(4))) float f32x4;
typedef __attribute__((ext_vector_type(8))) short bf16x8;
typedef __attribute__((ext_vector_type(4))) int   i32x4;

template<int N> struct ICn { static constexpr int value = N; };

__device__ __forceinline__ unsigned short f2bf(float f) {
  unsigned u = __float_as_uint(f);
  u += 0x7FFFu + ((u >> 16) & 1u);   // round-to-nearest-even
  return (unsigned short)(u >> 16);
}

__device__ __forceinline__ void load_lds16(const void* g, void* l) {
  __builtin_amdgcn_global_load_lds((const GLOBAL_AS void*)g, (LDS_AS void*)l, 16, 0, 0);
}

// ds_read_b128 with compile-time offset immediate; address VALU-free.
template<int IMM, typename T>
__device__ __forceinline__ void ds_read128t(T &d, unsigned addr) {
  asm volatile("ds_read_b128 %0, %1 offset:%c2"
               : "=&v"(d) : "v"(addr), "i"(IMM));
}

#define SBAR0 __builtin_amdgcn_sched_barrier(0)

#define WAITV(N) do { SBAR0; \
  asm volatile("s_waitcnt vmcnt(" #N ")" ::: "memory"); SBAR0; } while (0)

#define WAITVL(N) do { SBAR0; \
  asm volatile("s_waitcnt vmcnt(" #N ") lgkmcnt(0)" ::: "memory"); SBAR0; } while (0)

#define LGKMW(N) do { SBAR0; \
  asm volatile("s_waitcnt lgkmcnt(" #N ")" ::: "memory"); SBAR0; } while (0)

// ---------------------------------------------------------------------------
// Detect int8 vs int32 storage of the ternary weights (see round-0 notes).
// ---------------------------------------------------------------------------
__global__ __launch_bounds__(256) void detect_dtype_k(const int* __restrict__ w,
                                                      int* __restrict__ flag) {
  __shared__ int bad;
  if (threadIdx.x == 0) bad = 0;
  __syncthreads();
  int b = 0;
  for (int i = threadIdx.x; i < 4096; i += 256) {
    int v = w[i];
    if (v < -1 || v > 1) b = 1;
  }
  if (b) bad = 1;
  __syncthreads();
  if (threadIdx.x == 0) *flag = bad ? 0 : 1;
}

// ---------------------------------------------------------------------------
// x0[t][h] = bf16(emb[ids[t]][h])
// ---------------------------------------------------------------------------
__global__ __launch_bounds__(256) void gather_emb_k(const int* __restrict__ ids,
                                                    const float* __restrict__ emb,
                                                    unsigned short* __restrict__ x) {
  const int t = blockIdx.x;
  const int row = ids[t];
  const float4* src = (const float4*)(emb + (size_t)row * 2048);
  const int e = threadIdx.x;
  float4 a = src[e * 2], b = src[e * 2 + 1];
  uint4 o;
  o.x = f2bf(a.x) | ((unsigned)f2bf(a.y) << 16);
  o.y = f2bf(a.z) | ((unsigned)f2bf(a.w) << 16);
  o.z = f2bf(b.x) | ((unsigned)f2bf(b.y) << 16);
  o.w = f2bf(b.z) | ((unsigned)f2bf(b.w) << 16);
  *(uint4*)(x + (size_t)t * 2048 + e * 8) = o;
}

// ---------------------------------------------------------------------------
// ternary int8-or-int32 -> bf16 (hidden-layer weights)
// ---------------------------------------------------------------------------
__global__ __launch_bounds__(256) void convert_w_k(const void* __restrict__ src,
                                                   unsigned short* __restrict__ dst,
                                                   const int* __restrict__ flag) {
  const long long idx = ((long long)blockIdx.x * 256 + threadIdx.x) * 8;
  int v[8];
  if (*flag) {
    const int* s = (const int*)src + idx;
    const int4 a = *(const int4*)s;
    const int4 b = *(const int4*)(s + 4);
    v[0] = a.x; v[1] = a.y; v[2] = a.z; v[3] = a.w;
    v[4] = b.x; v[5] = b.y; v[6] = b.z; v[7] = b.w;
  } else {
    const uint2 u = *(const uint2*)((const char*)src + idx);
    v[0] = (char)(u.x); v[1] = (char)(u.x >> 8); v[2] = (char)(u.x >> 16); v[3] = (char)(u.x >> 24);
    v[4] = (char)(u.y); v[5] = (char)(u.y >> 8); v[6] = (char)(u.y >> 16); v[7] = (char)(u.y >> 24);
  }
  unsigned short o[8];
  #pragma unroll
  for (int k = 0; k < 8; ++k)
    o[k] = (v[k] == 0) ? 0 : ((v[k] > 0) ? 0x3F80 : 0xBF80);
  uint4 w;
  w.x = o[0] | ((unsigned)o[1] << 16);
  w.y = o[2] | ((unsigned)o[3] << 16);
  w.z = o[4] | ((unsigned)o[5] << 16);
  w.w = o[6] | ((unsigned)o[7] << 16);
  *(uint4*)(dst + idx) = w;
}

// ---------------------------------------------------------------------------
// ternary int32 -> int8 pack (output weights). Early-exit if already int8.
// ---------------------------------------------------------------------------
__global__ __launch_bounds__(256) void pack_w8_k(const void* __restrict__ src,
                                                 signed char* __restrict__ dst,
                                                 const int* __restrict__ flag) {
  if (!*flag) return;   // already int8: consumers read the input directly
  const long long idx = ((long long)blockIdx.x * 256 + threadIdx.x) * 8;
  const int* s = (const int*)src + idx;
  const int4 a = *(const int4*)s;
  const int4 b = *(const int4*)(s + 4);
  uint2 o;
  o.x = ((unsigned)(unsigned char)(signed char)a.x)       |
        ((unsigned)(unsigned char)(signed char)a.y << 8)  |
        ((unsigned)(unsigned char)(signed char)a.z << 16) |
        ((unsigned)(unsigned char)(signed char)a.w << 24);
  o.y = ((unsigned)(unsigned char)(signed char)b.x)       |
        ((unsigned)(unsigned char)(signed char)b.y << 8)  |
        ((unsigned)(unsigned char)(signed char)b.z << 16) |
        ((unsigned)(unsigned char)(signed char)b.w << 24);
  *(uint2*)(dst + idx) = o;
}

// ---------------------------------------------------------------------------
// colsum_c = sum_k w8[c][k]  (ternary row sums, fp32 out).  1 wave per col.
// ---------------------------------------------------------------------------
__global__ __launch_bounds__(256) void colsum_k(const signed char* __restrict__ wp,
                                                const signed char* __restrict__ wr,
                                                const int* __restrict__ flag,
                                                float* __restrict__ cs) {
  const signed char* w = (*flag) ? wp : wr;
  const int lane = threadIdx.x & 63;
  const int c = blockIdx.x * 4 + (threadIdx.x >> 6);
  const int4* p = (const int4*)(w + (size_t)c * 2048 + lane * 32);
  const int4 a = p[0], b = p[1];
  int wds[8] = {a.x, a.y, a.z, a.w, b.x, b.y, b.z, b.w};
  int s = 0;
  #pragma unroll
  for (int k = 0; k < 8; ++k)
    #pragma unroll
    for (int bb = 0; bb < 4; ++bb)
      s += (signed char)(wds[k] >> (8 * bb));
  #pragma unroll
  for (int o = 32; o; o >>= 1) s += __shfl_xor(s, o);
  if (lane == 0) cs[c] = (float)s;
}

// ---------------------------------------------------------------------------
// Per-row offset quantization of final x: s=rowmax/255, m=127.5s,
// q = round(x/s - 127.5) in [-128,127].  One block per row.
// ---------------------------------------------------------------------------
__global__ __launch_bounds__(256) void rowquant_k(const unsigned short* __restrict__ x,
                                                  signed char* __restrict__ xq,
                                                  float* __restrict__ srow) {
  __shared__ float wmax[4];
  const int r = blockIdx.x;
  const int e = threadIdx.x;
  const uint4 u = *(const uint4*)(x + (size_t)r * 2048 + e * 8);
  unsigned wds[4] = {u.x, u.y, u.z, u.w};
  float v[8];
  #pragma unroll
  for (int k = 0; k < 4; ++k) {
    v[2 * k]     = __uint_as_float(wds[k] << 16);
    v[2 * k + 1] = __uint_as_float(wds[k] & 0xFFFF0000u);
  }
  float m = 0.0f;                       // x >= 0 post-ReLU
  #pragma unroll
  for (int k = 0; k < 8; ++k) m = fmaxf(m, v[k]);
  #pragma unroll
  for (int o = 32; o; o >>= 1) m = fmaxf(m, __shfl_xor(m, o));
  if ((threadIdx.x & 63) == 0) wmax[threadIdx.x >> 6] = m;
  __syncthreads();
  const float mx = fmaxf(fmaxf(wmax[0], wmax[1]), fmaxf(wmax[2], wmax[3]));
  const float inv = mx > 0.0f ? 255.0f / mx : 0.0f;
  unsigned b[8];
  #pragma unroll
  for (int k = 0; k < 8; ++k) {
    int q = __float2int_rn(v[k] * inv - 127.5f);
    q = q < -128 ? -128 : (q > 127 ? 127 : q);
    b[k] = (unsigned)(unsigned char)(signed char)q;
  }
  uint2 o;
  o.x = b[0] | (b[1] << 8) | (b[2] << 16) | (b[3] << 24);
  o.y = b[4] | (b[5] << 8) | (b[6] << 16) | (b[7] << 24);
  *(uint2*)(xq + (size_t)r * 2048 + e * 8) = o;
  if (threadIdx.x == 0) srow[r] = mx * (1.0f / 255.0f);
}

// ---------------------------------------------------------------------------
// Hidden-layer GEMM v2 (r12, passing):
// 128x128 bf16, BK=64, 4 waves, dbuf LDS, stage-at-tile-start, asm ds_read
// w/ imm offsets, XOR swizzle, counted lgkm slice read-ahead, 1 barrier/tile.
// ---------------------------------------------------------------------------
__global__ __launch_bounds__(256, 2) void gemm_bt2_k(
    const unsigned short* __restrict__ A,
    const unsigned short* __restrict__ Bw,
    const float* __restrict__ scale,
    const float* __restrict__ bias,
    unsigned short* __restrict__ Cout,
    int M, int N, int K)
{
  __shared__ unsigned short As[2 * 8192];
  __shared__ unsigned short Bs[2 * 8192];

  const int tid  = threadIdx.x;
  const int lane = tid & 63;
  const int wid  = tid >> 6;
  const int wm   = wid >> 1;
  const int wn   = wid & 1;
  const int l15  = lane & 15;
  const int l4   = lane >> 4;

  const int mBase = blockIdx.y * 128;
  const int nBase = blockIdx.x * 128;

  const int gsw = ((lane & 7) ^ (lane >> 3)) * 8;

  const unsigned asB = (unsigned)(size_t)(const LDS_AS unsigned short*)As;
  const unsigned bsB = (unsigned)(size_t)(const LDS_AS unsigned short*)Bs;
  const unsigned x7  = (unsigned)(l15 & 7);
  const unsigned vA0 = asB + (wm << 13) + l15 * 128 + ((((unsigned)l4    ) ^ x7) << 4);
  const unsigned vA1 = asB + (wm << 13) + l15 * 128 + ((((unsigned)l4 + 4) ^ x7) << 4);
  const unsigned vB0 = bsB + (wn << 13) + l15 * 128 + ((((unsigned)l4    ) ^ x7) << 4);
  const unsigned vB1 = bsB + (wn << 13) + l15 * 128 + ((((unsigned)l4 + 4) ^ x7) << 4);

  const unsigned short* pA[4];
  const unsigned short* pB[4];
  #pragma unroll
  for (int j = 0; j < 4; ++j) {
    const int row = (wid * 4 + j) * 8 + (lane >> 3);
    pA[j] = A  + (size_t)(mBase + row) * K + gsw;
    pB[j] = Bw + (size_t)(nBase + row) * K + gsw;
  }

  f32x4 acc[4][4];
  #pragma unroll
  for (int i = 0; i < 4; ++i)
    #pragma unroll
    for (int j = 0; j < 4; ++j)
      acc[i][j] = (f32x4){0.f, 0.f, 0.f, 0.f};

  const int nt = K >> 6;

  #pragma unroll
  for (int j = 0; j < 4; ++j)
    load_lds16(pA[j], As + (wid * 4 + j) * 512);
  #pragma unroll
  for (int j = 0; j < 4; ++j)
    load_lds16(pB[j], Bs + (wid * 4 + j) * 512);
  #pragma unroll
  for (int j = 0; j < 4; ++j) { pA[j] += 64; pB[j] += 64; }
  WAITV(0);
  __builtin_amdgcn_s_barrier();

  bf16x8 afA[4], afB[4], bfrA[4], bfrB[4];

  for (int t = 0; t < nt; ++t) {
    const unsigned po = (unsigned)(t & 1) * 16384u;
    const unsigned aA0 = vA0 + po, aA1 = vA1 + po;
    const unsigned aB0 = vB0 + po, aB1 = vB1 + po;
    unsigned short* dA = As + (size_t)((t + 1) & 1) * 8192;
    unsigned short* dB = Bs + (size_t)((t + 1) & 1) * 8192;
    const bool st = (t + 1 < nt);

    ds_read128t<0   >(afA[0], aA0); ds_read128t<2048>(afA[1], aA0);
    ds_read128t<4096>(afA[2], aA0); ds_read128t<6144>(afA[3], aA0);
    ds_read128t<0   >(bfrA[0], aB0); ds_read128t<2048>(bfrA[1], aB0);
    ds_read128t<4096>(bfrA[2], aB0); ds_read128t<6144>(bfrA[3], aB0);
    ds_read128t<0   >(afB[0], aA1); ds_read128t<2048>(afB[1], aA1);
    ds_read128t<4096>(afB[2], aA1); ds_read128t<6144>(afB[3], aA1);
    ds_read128t<0   >(bfrB[0], aB1); ds_read128t<2048>(bfrB[1], aB1);
    ds_read128t<4096>(bfrB[2], aB1); ds_read128t<6144>(bfrB[3], aB1);
    #pragma unroll
    for (int j = 0; j < 4; ++j)
      load_lds16(st ? pA[j] : A, dA + (wid * 4 + j) * 512);
    #pragma unroll
    for (int j = 0; j < 4; ++j)
      load_lds16(st ? pB[j] : Bw, dB + (wid * 4 + j) * 512);
    #pragma unroll
    for (int j = 0; j < 4; ++j) { pA[j] += 64; pB[j] += 64; }

    LGKMW(8);
    __builtin_amdgcn_s_setprio(1);
    #pragma unroll
    for (int i = 0; i < 4; ++i)
      #pragma unroll
      for (int j = 0; j < 4; ++j)
        acc[i][j] = __builtin_amdgcn_mfma_f32_16x16x32_bf16(afA[i], bfrA[j], acc[i][j], 0, 0, 0);
    __builtin_amdgcn_s_setprio(0);
    SBAR0;
    LGKMW(0);
    __builtin_amdgcn_s_setprio(1);
    #pragma unroll
    for (int i = 0; i < 4; ++i)
      #pragma unroll
      for (int j = 0; j < 4; ++j)
        acc[i][j] = __builtin_amdgcn_mfma_f32_16x16x32_bf16(afB[i], bfrB[j], acc[i][j], 0, 0, 0);
    __builtin_amdgcn_s_setprio(0);
    SBAR0;
    WAITV(0);
    __builtin_amdgcn_s_barrier();
  }

  const int lr = l4;
  const int lc = l15;
  #pragma unroll
  for (int j = 0; j < 4; ++j) {
    const int col = nBase + wn * 64 + j * 16 + lc;
    const float sc = scale[col];
    const float bs = bias[col];
    #pragma unroll
    for (int i = 0; i < 4; ++i) {
      const int r0 = mBase + wm * 64 + i * 16 + lr * 4;
      #pragma unroll
      for (int r = 0; r < 4; ++r) {
        float vv = fmaxf(acc[i][j][r] * sc + bs, 0.0f);
        Cout[(size_t)(r0 + r) * N + col] = f2bf(vv);
      }
    }
  }
}

// ---------------------------------------------------------------------------
// Final GEMM (r7 known-good): INT8, free-running 2-barrier-per-tile.
// 256x256 tile, BK=128, 16 K-tiles, 8 waves (2Mx4N), dbuf LDS (128 KiB).
// ---------------------------------------------------------------------------

#define RD_B8() do { \
  ds_read128t<PAR*32768 +    0>(bfr[0][0], vB0); ds_read128t<PAR*32768 +    0>(bfr[0][1], vB1); \
  ds_read128t<PAR*32768 + 2048>(bfr[1][0], vB0); ds_read128t<PAR*32768 + 2048>(bfr[1][1], vB1); \
  ds_read128t<PAR*32768 + 4096>(bfr[2][0], vB0); ds_read128t<PAR*32768 + 4096>(bfr[2][1], vB1); \
  ds_read128t<PAR*32768 + 6144>(bfr[3][0], vB0); ds_read128t<PAR*32768 + 6144>(bfr[3][1], vB1); \
} while (0)

#define RD_A2(dst, R) do { \
  ds_read128t<PAR*32768 + (R)*2048       >(dst[0][0], vA0); ds_read128t<PAR*32768 + (R)*2048       >(dst[0][1], vA1); \
  ds_read128t<PAR*32768 + (R)*2048 + 2048>(dst[1][0], vA0); ds_read128t<PAR*32768 + (R)*2048 + 2048>(dst[1][1], vA1); \
} while (0)

#define STAGE_A(h) do { if (t >= 1 && t + 1 < nt) { \
  load_lds16(pA[h][0], Asf + (PAR ^ 1) * 32768 + (h) * 16384 +        wid * 1024); \
  load_lds16(pA[h][1], Asf + (PAR ^ 1) * 32768 + (h) * 16384 + 8192 + wid * 1024); \
  pA[h][0] += 128; pA[h][1] += 128; } } while (0)

#define STAGE_B(h) do { if (t + 2 < nt) { \
  load_lds16(pB[h][0], Bsf + PAR * 32768 + (h) * 16384 +        wid * 1024); \
  load_lds16(pB[h][1], Bsf + PAR * 32768 + (h) * 16384 + 8192 + wid * 1024); \
  pB[h][0] += 128; pB[h][1] += 128; } } while (0)

#define MFMA_PH(IP, AF) do { \
  __builtin_amdgcn_s_setprio(1); \
  { _Pragma("unroll") for (int ii = 0; ii < 2; ++ii) { \
      _Pragma("unroll") for (int j = 0; j < 4; ++j) { \
        acc[(IP)*2+ii][j] = __builtin_amdgcn_mfma_i32_16x16x64_i8(AF[ii][0], bfr[j][0], acc[(IP)*2+ii][j], 0, 0, 0); \
        acc[(IP)*2+ii][j] = __builtin_amdgcn_mfma_i32_16x16x64_i8(AF[ii][1], bfr[j][1], acc[(IP)*2+ii][j], 0, 0, 0); \
  } } } \
  __builtin_amdgcn_s_setprio(0); \
  SBAR0; \
} while (0)

__global__ __launch_bounds__(512, 2) void gemm256i8_k(
    const signed char* __restrict__ Aq,
    const signed char* __restrict__ Bpk,
    const signed char* __restrict__ Braw,
    const int* __restrict__ flag,
    const float* __restrict__ scale,
    const float* __restrict__ bias,
    const float* __restrict__ srow,
    const float* __restrict__ colsum,
    float* __restrict__ C,
    int M, int N, int K)   // K in elements (=bytes)
{
  __shared__ signed char Asf[2 * 32768];
  __shared__ signed char Bsf[2 * 32768];

  const signed char* Bq = (*flag) ? Bpk : Braw;

  const int tid  = threadIdx.x;
  const int lane = tid & 63;
  const int wid  = tid >> 6;   // 0..7
  const int wm   = wid >> 2;   // 0..1
  const int wn   = wid & 3;    // 0..3
  const int l15  = lane & 15;
  const int l4   = lane >> 4;

  // bijective XCD swizzle (2000 = 8*250), then m-fastest for B reuse
  const int q    = gridDim.x >> 3;
  const int wgid = (blockIdx.x & 7) * q + (blockIdx.x >> 3);
  const int mBase = (wgid & 15) << 8;
  const int nBase = (wgid >> 4) << 8;

  const int gsw = ((lane & 7) ^ (lane >> 3)) * 16;   // bytes

  const unsigned asB = (unsigned)(size_t)(const LDS_AS signed char*)Asf;
  const unsigned bsB = (unsigned)(size_t)(const LDS_AS signed char*)Bsf;
  const unsigned x7  = (unsigned)(l15 & 7);
  const unsigned vA0 = asB + (wm << 14) + l15 * 128 + ((((unsigned)l4    ) ^ x7) << 4);
  const unsigned vA1 = asB + (wm << 14) + l15 * 128 + ((((unsigned)l4 + 4) ^ x7) << 4);
  const unsigned vB0 = bsB + (wn << 13) + l15 * 128 + ((((unsigned)l4    ) ^ x7) << 4);
  const unsigned vB1 = bsB + (wn << 13) + l15 * 128 + ((((unsigned)l4 + 4) ^ x7) << 4);

  // persistent stage source pointers [half][j]
  const signed char* pA[2][2];
  const signed char* pB[2][2];
  #pragma unroll
  for (int h = 0; h < 2; ++h)
    #pragma unroll
    for (int j = 0; j < 2; ++j) {
      const int row = h * 128 + j * 64 + wid * 8 + (lane >> 3);
      pA[h][j] = Aq + (size_t)(mBase + row) * K + gsw;
      pB[h][j] = Bq + (size_t)(nBase + row) * K + gsw;
    }

  i32x4 acc[8][4];
  #pragma unroll
  for (int i = 0; i < 8; ++i)
    #pragma unroll
    for (int j = 0; j < 4; ++j)
      acc[i][j] = (i32x4){0, 0, 0, 0};

  const int nt = K >> 7;   // 16 K-tiles (even)

  // prologue: stage tile 0 then tile 1
  #pragma unroll
  for (int h = 0; h < 2; ++h)
    #pragma unroll
    for (int j = 0; j < 2; ++j)
      load_lds16(pA[h][j], Asf + h * 16384 + j * 8192 + wid * 1024);
  #pragma unroll
  for (int h = 0; h < 2; ++h)
    #pragma unroll
    for (int j = 0; j < 2; ++j)
      load_lds16(pB[h][j], Bsf + h * 16384 + j * 8192 + wid * 1024);
  #pragma unroll
  for (int h = 0; h < 2; ++h)
    #pragma unroll
    for (int j = 0; j < 2; ++j)
      load_lds16(pA[h][j] + 128, Asf + 32768 + h * 16384 + j * 8192 + wid * 1024);
  #pragma unroll
  for (int h = 0; h < 2; ++h)
    #pragma unroll
    for (int j = 0; j < 2; ++j)
      load_lds16(pB[h][j] + 128, Bsf + 32768 + h * 16384 + j * 8192 + wid * 1024);
  #pragma unroll
  for (int h = 0; h < 2; ++h)
    #pragma unroll
    for (int j = 0; j < 2; ++j) { pA[h][j] += 256; pB[h][j] += 256; }

  asm volatile("s_waitcnt vmcnt(8)" ::: "memory");   // tile 0 landed
  __builtin_amdgcn_s_barrier();

  i32x4 bfr[4][2];
  i32x4 afP[2][2], afQ[2][2];

  auto tile_body = [&](int t, auto par_c) {
    constexpr int PAR = decltype(par_c)::value;
    // ---- p0 : rows01 + all B + rows23 (16 reads); retire first 12 ----
    RD_A2(afP, 0);
    RD_B8();
    RD_A2(afQ, 2);
    STAGE_A(0);
    LGKMW(4);
    MFMA_PH(0, afP);
    // ---- p1 ----
    RD_A2(afP, 4);
    STAGE_A(1);
    LGKMW(4);
    MFMA_PH(1, afQ);
    __builtin_amdgcn_s_barrier();   // #1: all waves' B-frag reads retired
    // ---- p2 ----
    RD_A2(afQ, 6);
    STAGE_B(0);
    LGKMW(4);
    MFMA_PH(2, afP);
    // ---- p3 ----
    STAGE_B(1);
    LGKMW(0);
    MFMA_PH(3, afQ);
    if (t + 2 < nt) { WAITV(4); }
    else            { WAITV(0); }
    __builtin_amdgcn_s_barrier();   // #2: tile end
  };

  for (int t = 0; t < nt; t += 2) {
    tile_body(t,     ICn<0>{});
    tile_body(t + 1, ICn<1>{});
  }

  // epilogue: C/D layout col = lane&15, row = (lane>>4)*4 + reg (dtype-indep)
  #pragma unroll
  for (int j = 0; j < 4; ++j) {
    const int col = nBase + wn * 64 + j * 16 + l15;
    const float sc  = scale[col];
    const float csc = colsum[col] * sc;
    const float bs  = bias[col];
    #pragma unroll
    for (int i = 0; i < 8; ++i) {
      const int r0 = mBase + wm * 128 + i * 16 + l4 * 4;
      const f32x4 sv = *(const f32x4*)(srow + r0);
      #pragma unroll
      for (int r = 0; r < 4; ++r) {
        const float fa = (float)acc[i][j][r];
        C[(size_t)(r0 + r) * N + col] =
            fmaf(fa, sv[r] * sc, fmaf(127.5f * sv[r], csc, bs));
      }
    }
  }
}

// ---------------------------------------------------------------------------
extern "C" void kernel_launch(void* const* d_in, const int* in_sizes, int n_in,
                              void* d_out, int out_size, void* d_ws, size_t ws_size,
                              hipStream_t stream) {
  const int V = 32000, H = 2048, L = 4, M = 4096;
  const int*   ids         = (const int*)d_in[0];
  const float* emb         = (const float*)d_in[1];
  const void*  layer_wq    = d_in[2];
  const float* layer_scale = (const float*)d_in[3];
  const float* layer_bias  = (const float*)d_in[4];
  const void*  out_wq      = d_in[5];
  const float* out_scale   = (const float*)d_in[6];
  const float* out_bias    = (const float*)d_in[7];
  float* out = (float*)d_out;

  char* ws = (char*)d_ws;
  const size_t xBytes = (size_t)M * H * 2;
  unsigned short* xA  = (unsigned short*)(ws);
  unsigned short* xB  = (unsigned short*)(ws + xBytes);
  unsigned short* lw  = (unsigned short*)(ws + 2 * xBytes);
  size_t off = 2 * xBytes + (size_t)L * H * H * 2;
  signed char* ow8    = (signed char*)(ws + off);   off += (size_t)V * H;
  signed char* xq     = (signed char*)(ws + off);   off += (size_t)M * H;
  float* srow         = (float*)(ws + off);         off += (size_t)M * 4;
  float* cs           = (float*)(ws + off);         off += (size_t)V * 4;
  int* flag           = (int*)(ws + off);

  detect_dtype_k<<<1, 256, 0, stream>>>((const int*)layer_wq, flag);
  gather_emb_k<<<M, 256, 0, stream>>>(ids, emb, xA);
  convert_w_k<<<(L * H * H) / 2048, 256, 0, stream>>>(layer_wq, lw, flag);
  pack_w8_k<<<(V * H) / 2048, 256, 0, stream>>>(out_wq, ow8, flag);
  colsum_k<<<V / 4, 256, 0, stream>>>(ow8, (const signed char*)out_wq, flag, cs);

  dim3 blk(256);
  dim3 gh(H / 128, M / 128);
  unsigned short* xin = xA;
  unsigned short* xout = xB;
  for (int i = 0; i < L; ++i) {
    gemm_bt2_k<<<gh, blk, 0, stream>>>(xin, lw + (size_t)i * H * H,
                                       layer_scale + i * H, layer_bias + i * H,
                                       xout, M, H, H);
    unsigned short* t = xin; xin = xout; xout = t;
  }

  rowquant_k<<<M, 256, 0, stream>>>(xin, xq, srow);

  // final: (M/256)*(V/256) = 16*125 = 2000 blocks
  gemm256i8_k<<<dim3(2000), dim3(512), 0, stream>>>(
      xq, ow8, (const signed char*)out_wq, flag,
      out_scale, out_bias, srow, cs, out, M, V, H);
}